// Round 3
// baseline (248.119 us; speedup 1.0000x reference)
//
#include <hip/hip_runtime.h>

// RollingBufferCache: B=4, H=8, S=512, D=128, BUF=4096, cur_len=6144 (>BUF)
// Output = concat(k_window, v_window), each [B,H,W,D], W = min(cur_len,BUF) = 4096.
// No cache write-back: reference returns only the gathered windows.
// Output row t -> physical row p = (cur_len - W + t) % BUF. If p is inside the
// circular scatter range [(cur_len-S)%BUF, +S) the source is the new k/v chunk.
//
// R1 lesson: 1 outstanding load/wave = latency-bound at 2.5 TB/s. This version
// issues 8 independent 16B loads per thread (K+V fused, 4x unroll) before any
// store, 32-bit shift/and index math, nontemporal stores.
// R2 fix: __builtin_nontemporal_store needs a native clang vector type, not
// HIP_vector_type -> use ext_vector_type(4) float throughout.

typedef float fvec4 __attribute__((ext_vector_type(4)));

constexpr int Bc   = 4;
constexpr int Hc   = 8;
constexpr int Sc   = 512;
constexpr int Dc   = 128;
constexpr int BUFc = 4096;
constexpr int D4   = Dc / 4;                    // 32 fvec4 per row
constexpr int Wc   = BUFc;                      // window = min(6144,4096)
constexpr int HALF = Bc * Hc * Wc * D4;         // 4,194,304 fvec4 per tensor
constexpr int UNROLL = 4;
constexpr int THREADS = 256;
constexpr int GRID = HALF / (THREADS * UNROLL); // 4096 blocks, exact cover

static_assert(GRID * THREADS * UNROLL == HALF, "exact grid cover");

__global__ __launch_bounds__(THREADS)
void RollingBufferCache_kernel(const fvec4* __restrict__ kn,   // [B,H,S,D]
                               const fvec4* __restrict__ vn,   // [B,H,S,D]
                               const fvec4* __restrict__ kc,   // [B,H,BUF,D]
                               const fvec4* __restrict__ vc,   // [B,H,BUF,D]
                               const int*   __restrict__ curp,
                               fvec4*       __restrict__ out)  // [2,B,H,W,D]
{
    const int cur       = *curp;                    // uniform scalar load
    const int window    = (cur < Wc) ? cur : Wc;    // = 4096 here
    const int start_w   = cur - window;             // logical window start
    const int start_idx = (cur - Sc) & (BUFc - 1);  // scatter start

    const int base = blockIdx.x * (THREADS * UNROLL) + threadIdx.x;

    fvec4 kv[UNROLL];
    fvec4 vv[UNROLL];
    int   oj[UNROLL];

    // Phase 1: issue all 8 loads (4 K + 4 V), fully independent.
    #pragma unroll
    for (int u = 0; u < UNROLL; ++u) {
        const int j  = base + u * THREADS;          // coalesced within wave
        const int d4 = j & (D4 - 1);                // j % 32
        const int t  = (j >> 5) & (Wc - 1);         // row within window
        const int bh = j >> 17;                     // batch*head index

        const int p   = (start_w + t) & (BUFc - 1); // physical cache row
        const int off = (p - start_idx) & (BUFc - 1);
        const bool in_new = (off < Sc);

        const int cj = (bh << 17) + (p << 5) + d4;  // cache offset (fvec4)
        const int nj = (bh << 14) + (off << 5) + d4;// new-chunk offset

        const fvec4* __restrict__ sk = in_new ? kn : kc;
        const fvec4* __restrict__ sv = in_new ? vn : vc;
        const int o = in_new ? nj : cj;

        kv[u] = sk[o];
        vv[u] = sv[o];
        oj[u] = j;
    }

    // Phase 2: stores. Nontemporal: output is never re-read by this kernel,
    // keep L3 input residency intact.
    #pragma unroll
    for (int u = 0; u < UNROLL; ++u) {
        __builtin_nontemporal_store(kv[u], &out[oj[u]]);
        __builtin_nontemporal_store(vv[u], &out[HALF + oj[u]]);
    }
}

extern "C" void kernel_launch(void* const* d_in, const int* in_sizes, int n_in,
                              void* d_out, int out_size, void* d_ws, size_t ws_size,
                              hipStream_t stream) {
    const fvec4* kn   = (const fvec4*)d_in[0];
    const fvec4* vn   = (const fvec4*)d_in[1];
    const fvec4* kc   = (const fvec4*)d_in[2];
    const fvec4* vc   = (const fvec4*)d_in[3];
    const int*   curp = (const int*) d_in[4];
    fvec4*       out  = (fvec4*)     d_out;

    RollingBufferCache_kernel<<<GRID, THREADS, 0, stream>>>(kn, vn, kc, vc, curp, out);
}

// Round 4
// 245.439 us; speedup vs baseline: 1.0109x; 1.0109x over previous
//
#include <hip/hip_runtime.h>

// RollingBufferCache as a segmented memcpy.
// B=4,H=8,S=512,D=128,BUF=4096, cur_len=6144. W = min(cur,BUF) = 4096.
// Output row t of (z,bh) comes from physical row p=(cur-W+t)%BUF; p is in the
// circular scatter range [start_idx, start_idx+S) -> source is the new chunk
// at row off=(p-start_idx)%BUF, else the cache at row p.
//
// Key structural fact (cur=6144): the region boundaries in t (wrap at t=2048,
// new-chunk at t=3584) are 64-row aligned, so a block owning 64 consecutive
// output rows of one tensor has a UNIFORM source (one pointer + contiguous
// range). Each block is a pure 32KiB->32KiB contiguous copy: one read stream,
// one write stream per wave — matching the m13 copy-benchmark structure.
// (Assumes cur % 64 == 0 and S % 64 == 0; true for this problem.)
//
// R3 post-mortem: 8-deep MLP gave 0 gain (2.46 TB/s both rounds) -> limiter is
// not latency; hypothesis now = multi-stream interleaving per wave.

typedef float fvec4 __attribute__((ext_vector_type(4)));

constexpr int Bc   = 4;
constexpr int Hc   = 8;
constexpr int Sc   = 512;
constexpr int Dc   = 128;
constexpr int BUFc = 4096;
constexpr int D4   = Dc / 4;            // 32 fvec4 per row
constexpr int Wc   = BUFc;              // window rows
constexpr int NBH  = Bc * Hc;           // 32
constexpr int CHUNK_ROWS = 64;          // rows per block (divides 2048, 3584, 4096)
constexpr int THREADS = 256;
constexpr int PER_THREAD = CHUNK_ROWS * D4 / THREADS;     // 8 fvec4
constexpr int CHUNKS_PER_BH = Wc / CHUNK_ROWS;            // 64
constexpr int GRID = 2 * NBH * CHUNKS_PER_BH;             // 4096 blocks

static_assert(PER_THREAD == 8, "8 fvec4 per thread");

__global__ __launch_bounds__(THREADS)
void RollingBufferCache_kernel(const fvec4* __restrict__ kn,   // [B,H,S,D]
                               const fvec4* __restrict__ vn,   // [B,H,S,D]
                               const fvec4* __restrict__ kc,   // [B,H,BUF,D]
                               const fvec4* __restrict__ vc,   // [B,H,BUF,D]
                               const int*   __restrict__ curp,
                               fvec4*       __restrict__ out)  // [2,B,H,W,D]
{
    const int cur       = *curp;                     // uniform scalar
    const int window    = (cur < Wc) ? cur : Wc;     // 4096
    const int start_w   = cur - window;              // logical window start
    const int start_idx = (cur - Sc) & (BUFc - 1);   // scatter start

    const int bid   = blockIdx.x;
    const int chunk = bid & (CHUNKS_PER_BH - 1);     // 64 chunks per (z,bh)
    const int bh    = (bid >> 6) & (NBH - 1);
    const int z     = bid >> 11;                     // 0=K, 1=V

    const int r0   = chunk << 6;                     // first output row
    const int p0   = (start_w + r0) & (BUFc - 1);    // physical cache row
    const int offn = (p0 - start_idx) & (BUFc - 1);  // offset into scatter range
    const bool in_new = (offn < Sc);                 // block-uniform

    const fvec4* __restrict__ src =
        z ? (in_new ? vn : vc) : (in_new ? kn : kc);
    const int sbase = in_new ? (bh * Sc + offn) * D4
                             : (bh * BUFc + p0) * D4;
    const int dbase = ((z * NBH + bh) * Wc + r0) * D4;

    fvec4 r[PER_THREAD];
    #pragma unroll
    for (int u = 0; u < PER_THREAD; ++u)
        r[u] = src[sbase + u * THREADS + threadIdx.x];
    #pragma unroll
    for (int u = 0; u < PER_THREAD; ++u)
        out[dbase + u * THREADS + threadIdx.x] = r[u];
}

extern "C" void kernel_launch(void* const* d_in, const int* in_sizes, int n_in,
                              void* d_out, int out_size, void* d_ws, size_t ws_size,
                              hipStream_t stream) {
    const fvec4* kn   = (const fvec4*)d_in[0];
    const fvec4* vn   = (const fvec4*)d_in[1];
    const fvec4* kc   = (const fvec4*)d_in[2];
    const fvec4* vc   = (const fvec4*)d_in[3];
    const int*   curp = (const int*) d_in[4];
    fvec4*       out  = (fvec4*)     d_out;

    RollingBufferCache_kernel<<<GRID, THREADS, 0, stream>>>(kn, vn, kc, vc, curp, out);
}